// Round 16
// baseline (142.880 us; speedup 1.0000x reference)
//
#include <hip/hip_runtime.h>
#include <stdint.h>

// out = dequant( int8(lhs*ls) @ int8(rhs*rs) ) / (ls*rs), 4096^3, fp32 in/out.
// ls = 127 / max(amax|lhs|, 1e-12). Int core is bit-exact vs numpy (RNE quant).
//
// Workspace: [0,16Mi) qA frag-order ; [16Mi,32Mi) qBT frag-order ; 2x u32 amax.
//
// GEMM v15 = v14 wave-for-wave (frag-ordered workspace, 32x32x32 MFMA, A via
// conflict-free linear LDS prefetch-1, B global-direct register prefetch,
// BK=128 window, one barrier/window) re-partitioned 128x128 / 2 waves per
// block -> FOUR blocks (barrier domains) per CU. Trend: 1 domain (v13,
// 78.5us) -> 2 domains (v14, 72.5us, MfmaUtil 40.7): cross-domain dephasing
// fills the MFMA pipe during other domains' read/wait phases. Registers pin
// total waves at 8/CU (224 unified/wave, 2/SIMD), so domain count is the
// remaining axis: 4 domains of 2 waves. LDS 32 KB/block x4 = 128 <= 160.
//
// Layouts (all harness-verified, absmax 0.0 in v8/v10-v14):
//   frag (t_g, ks_g) at ((t_g*128 + ks_g)*64 + lane)*16; lane l holds
//   [t_g*32+(l&31)][ks_g*32+(l>>5)*16 .. +16).
//   C/D 32x32: col = lane&31, row = (reg&3) + 8*(reg>>2) + 4*(lane>>5).

#define NROW 4096
#define NELEM (4096 * 4096)

typedef __attribute__((ext_vector_type(4))) int int32x4;
typedef __attribute__((ext_vector_type(16))) int int32x16;
typedef const __attribute__((address_space(1))) int8_t* gptr1_t;
typedef __attribute__((address_space(3))) int8_t* lptr3_t;

__global__ void absmax_both_kernel(const float* __restrict__ lhs,
                                   const float* __restrict__ rhs,
                                   unsigned* __restrict__ amax) {
    __shared__ float red[4];
    const int t = blockIdx.x & 1;
    const float4* x4 = (const float4*)(t ? rhs : lhs);
    const int bid = blockIdx.x >> 1;
    const int stride = (gridDim.x >> 1) * blockDim.x;  // 262144
    int i = bid * blockDim.x + threadIdx.x;
    float m0 = 0.0f, m1 = 0.0f, m2 = 0.0f, m3 = 0.0f;
    for (; i + 3 * stride < NELEM / 4; i += 4 * stride) {
        float4 a = x4[i];
        float4 b = x4[i + stride];
        float4 c = x4[i + 2 * stride];
        float4 d = x4[i + 3 * stride];
        m0 = fmaxf(m0, fmaxf(fmaxf(fabsf(a.x), fabsf(a.y)),
                             fmaxf(fabsf(a.z), fabsf(a.w))));
        m1 = fmaxf(m1, fmaxf(fmaxf(fabsf(b.x), fabsf(b.y)),
                             fmaxf(fabsf(b.z), fabsf(b.w))));
        m2 = fmaxf(m2, fmaxf(fmaxf(fabsf(c.x), fabsf(c.y)),
                             fmaxf(fabsf(c.z), fabsf(c.w))));
        m3 = fmaxf(m3, fmaxf(fmaxf(fabsf(d.x), fabsf(d.y)),
                             fmaxf(fabsf(d.z), fabsf(d.w))));
    }
    for (; i < NELEM / 4; i += stride) {
        float4 a = x4[i];
        m0 = fmaxf(m0, fmaxf(fmaxf(fabsf(a.x), fabsf(a.y)),
                             fmaxf(fabsf(a.z), fabsf(a.w))));
    }
    float m = fmaxf(fmaxf(m0, m1), fmaxf(m2, m3));
    for (int off = 32; off > 0; off >>= 1)
        m = fmaxf(m, __shfl_down(m, off, 64));
    const int lane = threadIdx.x & 63, wave = threadIdx.x >> 6;
    if (lane == 0) red[wave] = m;
    __syncthreads();
    if (threadIdx.x == 0) {
        float b = fmaxf(fmaxf(red[0], red[1]), fmaxf(red[2], red[3]));
        atomicMax(amax + t, __float_as_uint(b));  // |x|>=0: bits monotone as uint
    }
}

__device__ __forceinline__ int q8(float v, float s) {
    int r = __float2int_rn(v * s);  // RNE, matches jnp.round
    r = r < -127 ? -127 : r;
    r = r > 127 ? 127 : r;
    return r;
}

__device__ __forceinline__ int pack4(float a, float b, float c, float d,
                                     float s) {
    return (q8(a, s) & 0xff) | ((q8(b, s) & 0xff) << 8) |
           ((q8(c, s) & 0xff) << 16) | ((q8(d, s) & 0xff) << 24);
}

// Blocks [0,4096): A -> fragment layout (thread t = chunk c: contiguous 16B
// store to qA+c*16 from a 64B row-segment of lhs). Blocks [4096,8192): B ->
// verified LDS 64x64 transpose, frag-order output. (v10-v14 verified.)
__global__ void quant_kernel(const float* __restrict__ lhs,
                             const float* __restrict__ rhs,
                             int8_t* __restrict__ qA, int8_t* __restrict__ qT,
                             const unsigned* __restrict__ amax) {
    __shared__ int8_t sm[64][68];
    if (blockIdx.x < 4096) {
        const float s = 127.0f / fmaxf(__uint_as_float(amax[0]), 1e-12f);
        const int c = blockIdx.x * 256 + threadIdx.x;
        const int l = c & 63;
        const int ks_g = (c >> 6) & 127;
        const int mt_g = c >> 13;
        const int row = mt_g * 32 + (l & 31);
        const int kb = ks_g * 32 + (l >> 5) * 16;
        const float4* src = (const float4*)(lhs + (size_t)row * NROW + kb);
        float4 v0 = src[0], v1 = src[1], v2 = src[2], v3 = src[3];
        int4 w;
        w.x = pack4(v0.x, v0.y, v0.z, v0.w, s);
        w.y = pack4(v1.x, v1.y, v1.z, v1.w, s);
        w.z = pack4(v2.x, v2.y, v2.z, v2.w, s);
        w.w = pack4(v3.x, v3.y, v3.z, v3.w, s);
        *(int4*)(qA + (size_t)c * 16) = w;
    } else {
        const float s = 127.0f / fmaxf(__uint_as_float(amax[1]), 1e-12f);
        const int b = blockIdx.x - 4096;
        const int n0 = (b & 63) * 64, k0 = (b >> 6) * 64;
        const int rl = threadIdx.x >> 4;   // k row within 16-row slab
        const int nq = threadIdx.x & 15;   // float4 column
        for (int r = 0; r < 4; ++r) {
            const int kl = r * 16 + rl;
            float4 v = *(const float4*)(rhs + (size_t)(k0 + kl) * NROW + n0 + nq * 4);
            sm[nq * 4 + 0][kl] = (int8_t)q8(v.x, s);
            sm[nq * 4 + 1][kl] = (int8_t)q8(v.y, s);
            sm[nq * 4 + 2][kl] = (int8_t)q8(v.z, s);
            sm[nq * 4 + 3][kl] = (int8_t)q8(v.w, s);
        }
        __syncthreads();
        // Frag-order store: tile = 2 nt x 2 ks x 64 lanes = 256 chunks.
        const int nt_l = threadIdx.x >> 7;        // 0..1
        const int ks_l = (threadIdx.x >> 6) & 1;  // 0..1
        const int l = threadIdx.x & 63;
        const int n_loc = nt_l * 32 + (l & 31);
        const int k_loc = ks_l * 32 + (l >> 5) * 16;
        int4 w;  // 4x b32 reads, stride 17 words -> conflict-free
        w.x = *(const int*)&sm[n_loc][k_loc + 0];
        w.y = *(const int*)&sm[n_loc][k_loc + 4];
        w.z = *(const int*)&sm[n_loc][k_loc + 8];
        w.w = *(const int*)&sm[n_loc][k_loc + 12];
        const int nt_g = (b & 63) * 2 + nt_l;
        const int ks_g = (b >> 6) * 2 + ks_l;
        *(int4*)(qT + (((size_t)nt_g * 128 + ks_g) * 64 + l) * 16) = w;
    }
}

// 128x128 tile, 2 waves (1Mx2N of 128x64 = 4x2 of 32x32), BK=128 windows,
// 4 blocks/CU. A: double-buffered frag-ordered LDS (2 x 16 KiB), prefetch-1.
// B: global-direct register frags, half-window (2 ks) prefetch. Window w:
// [stage A(w+1); load B ks=2,3 of w; compute ks=0,1; load B ks=0,1 of w+1;
// compute ks=2,3; vmcnt(4); s_barrier]. Per-wave code identical to v13/v14.
__global__ __launch_bounds__(128, 2) void gemm_i8_kernel(
    const int8_t* __restrict__ qA, const int8_t* __restrict__ qBT,
    float* __restrict__ out, const unsigned* __restrict__ amax) {
    __shared__ __align__(16) int8_t sA[2][16384];

    const int tid = threadIdx.x;
    const int lane = tid & 63;
    const int wn = tid >> 6;        // 0..1 : 64-col sub-tile

    // XCD-aware bijective swizzle (grid 1024, 1024%8==0): XCD k gets swz ids
    // [128k,128k+128) -> 4 contiguous 128-row M-panels (2 MB A) L2-resident.
    const int bid = blockIdx.y * 32 + blockIdx.x;
    const int swz = (bid & 7) * 128 + (bid >> 3);
    const int m0 = (swz >> 5) * 128, n0 = (swz & 31) * 128;

    const int rl = lane & 31;       // row within a 32-row MFMA tile
    const int hi = lane >> 5;       // k-half selector

    // A staging: 1024 chunks x 16 B per K-tile (16 frags x 64 lanes), 8 per
    // thread. Chunk c = tid + j*128: lane = c&63 = tid&63, frag f = c>>6 =
    // (tid>>6) + 2j. Src = (m0/32 + (f>>2))*131072 + (kt*4 + (f&3))*1024 +
    // (c&63)*16; dst = slot*16384 + c*16 (= f*1024 + (c&63)*16).
    const int w2 = tid >> 6;
    const gptr1_t pA0 = (gptr1_t)(qA + (size_t)(m0 / 32) * 131072 +
                                  (tid & 63) * 16);
    int8_t* sAf = &sA[0][0];

    auto stage = [&](int slot, int kt) {
        const int kb = kt * 4096;
#pragma unroll
        for (int j = 0; j < 8; ++j) {
            const int f = w2 + 2 * j;
            __builtin_amdgcn_global_load_lds(
                pA0 + (size_t)(f >> 2) * 131072 + (f & 3) * 1024 + kb,
                (lptr3_t)(sAf + slot * 16384 + f * 1024 + (tid & 63) * 16),
                16, 0, 0);
        }
    };

    // B global-direct: frag (n0/32 + wn*2 + nt, kt*4 + ks) at
    // pbW + nt*131072 + (kt*4+ks)*1024, per-lane +lane*16.
    const int8_t* pbW = qBT + (size_t)(n0 / 32 + wn * 2) * 131072 + lane * 16;

    int32x16 acc[4][2];
#pragma unroll
    for (int mt = 0; mt < 4; ++mt)
#pragma unroll
        for (int nt = 0; nt < 2; ++nt) acc[mt][nt] = (int32x16)(0);

    // ds_read base: A-frag (mt, ks) at (mt*4+ks)*1024 + lane*16.
    const int aBase = lane * 16;

    int32x4 B0[4], B1[4];  // [nt*2 + k] for a 2-ks half-window

#define LOADB(B, KT, KS0)                                                     \
    {                                                                         \
        const int8_t* bp = pbW + (size_t)(KT)*4096 + (KS0)*1024;              \
        B[0] = *(const int32x4*)(bp);                                         \
        B[1] = *(const int32x4*)(bp + 1024);                                  \
        B[2] = *(const int32x4*)(bp + 131072);                                \
        B[3] = *(const int32x4*)(bp + 131072 + 1024);                         \
    }

#define HALF(APTR, B, KS0)                                                    \
    {                                                                         \
        _Pragma("unroll") for (int k = 0; k < 2; ++k) {                       \
            int32x4 af[4];                                                    \
            _Pragma("unroll") for (int mt = 0; mt < 4; ++mt) af[mt] =         \
                *(const int32x4*)((APTR) + aBase + mt * 4096 +                \
                                  ((KS0) + k) * 1024);                        \
            __builtin_amdgcn_s_setprio(1);                                    \
            _Pragma("unroll") for (int mt = 0; mt < 4; ++mt)                  \
                _Pragma("unroll") for (int nt = 0; nt < 2; ++nt)              \
                    acc[mt][nt] = __builtin_amdgcn_mfma_i32_32x32x32_i8(      \
                        af[mt], B[nt * 2 + k], acc[mt][nt], 0, 0, 0);         \
            __builtin_amdgcn_s_setprio(0);                                    \
        }                                                                     \
    }

    // Prologue: stage A tile 0; load B ks=0,1 of tile 0; drain; barrier.
    stage(0, 0);
    __builtin_amdgcn_sched_barrier(0);
    LOADB(B0, 0, 0)
    asm volatile("s_waitcnt vmcnt(0)" ::: "memory");
    __builtin_amdgcn_sched_barrier(0);
    __builtin_amdgcn_s_barrier();
    __builtin_amdgcn_sched_barrier(0);

    // 32 K-tiles of 128. Windows 0..30 stage the next tile; window 31 below.
#pragma unroll 1
    for (int w = 0; w < 31; ++w) {
        const int8_t* a = sAf + (w & 1) * 16384;
        stage((w + 1) & 1, w + 1);
        __builtin_amdgcn_sched_barrier(0);
        LOADB(B1, w, 2)       // this window's second half
        HALF(a, B0, 0)        // compute ks 0,1 (B0 loaded last window)
        LOADB(B0, w + 1, 0)   // next window's first half
        HALF(a, B1, 2)        // compute ks 2,3 (B1-wait retires stage too)
        asm volatile("s_waitcnt vmcnt(4)" ::: "memory");  // keep only B0(w+1)
        __builtin_amdgcn_sched_barrier(0);
        __builtin_amdgcn_s_barrier();
        __builtin_amdgcn_sched_barrier(0);
    }
    // Window 31 (slot 1): no staging.
    {
        const int8_t* a = sAf + 16384;
        LOADB(B1, 31, 2)
        HALF(a, B0, 0)
        HALF(a, B1, 2)
    }

    // Epilogue: dequant + store. 32x32 C/D layout: col = lane&31,
    // row = (reg&3) + 8*(reg>>2) + 4*(lane>>5). (v8/v12-v14-verified.)
    const float ls = 127.0f / fmaxf(__uint_as_float(amax[0]), 1e-12f);
    const float rs = 127.0f / fmaxf(__uint_as_float(amax[1]), 1e-12f);
    const float inv = 1.0f / (ls * rs);
#pragma unroll
    for (int mt = 0; mt < 4; ++mt)
#pragma unroll
        for (int nt = 0; nt < 2; ++nt)
#pragma unroll
            for (int reg = 0; reg < 16; ++reg) {
                const int row = m0 + mt * 32 + (reg & 3) + 8 * (reg >> 2) +
                                4 * hi;
                const int col = n0 + wn * 64 + nt * 32 + rl;
                out[(size_t)row * NROW + col] = (float)acc[mt][nt][reg] * inv;
            }
#undef LOADB
#undef HALF
}

extern "C" void kernel_launch(void* const* d_in, const int* in_sizes, int n_in,
                              void* d_out, int out_size, void* d_ws,
                              size_t ws_size, hipStream_t stream) {
    const float* lhs = (const float*)d_in[0];
    const float* rhs = (const float*)d_in[1];
    float* out = (float*)d_out;

    int8_t* qA = (int8_t*)d_ws;
    int8_t* qBT = qA + (size_t)16 * 1024 * 1024;
    unsigned* amax = (unsigned*)(qBT + (size_t)16 * 1024 * 1024);

    hipMemsetAsync(amax, 0, 8, stream);
    absmax_both_kernel<<<2048, 256, 0, stream>>>(lhs, rhs, amax);
    quant_kernel<<<4096 + 4096, 256, 0, stream>>>(lhs, rhs, qA, qBT, amax);
    gemm_i8_kernel<<<dim3(32, 32), 128, 0, stream>>>(qA, qBT, out, amax);
}

// Round 17
// 137.950 us; speedup vs baseline: 1.0357x; 1.0357x over previous
//
#include <hip/hip_runtime.h>
#include <stdint.h>

// out = dequant( int8(lhs*ls) @ int8(rhs*rs) ) / (ls*rs), 4096^3, fp32 in/out.
// ls = 127 / max(amax|lhs|, 1e-12). Int core is bit-exact vs numpy (RNE quant).
//
// Workspace: [0,16Mi) qA frag-order ; [16Mi,32Mi) qBT frag-order ; 2x u32 amax.
//
// GEMM v16 = v14 (best: 72.5us GEMM; 128x256 tile, 4 waves, frag-ordered
// workspace, 32x32x32 MFMA, A via linear LDS prefetch-1, B global-direct
// register prefetch, 2 blocks/CU for cross-domain MFMA/mem overlap) with
// BK=256 windows: HALF the barriers (16 vs 32). v15 showed the domain axis
// peaked at 2 (4 domains -> +38% FETCH, regressed); the remaining per-window
// cost is the barrier realignment tax (~400-600 cyc x 32). v6 proved window
// doubling at constant traffic is worth ~+12% on this op. A-LDS slots 32 KB
// (2 slots x 32 KB x 2 blocks = 128 KB <= 160); stage = 8 gload_lds/thread;
// B keeps 2-ks register prefetch, 4 quarter-phases/window, same in-order
// vmcnt discipline (compiler's B-wait before the last quarter drains the
// stage; vmcnt(4) keeps only next window's first B-group in flight).
//
// Layouts (all harness-verified, absmax 0.0 in v8/v10-v15):
//   frag (t_g, ks_g) at ((t_g*128 + ks_g)*64 + lane)*16; lane l holds
//   [t_g*32+(l&31)][ks_g*32+(l>>5)*16 .. +16).
//   C/D 32x32: col = lane&31, row = (reg&3) + 8*(reg>>2) + 4*(lane>>5).

#define NROW 4096
#define NELEM (4096 * 4096)

typedef __attribute__((ext_vector_type(4))) int int32x4;
typedef __attribute__((ext_vector_type(16))) int int32x16;
typedef const __attribute__((address_space(1))) int8_t* gptr1_t;
typedef __attribute__((address_space(3))) int8_t* lptr3_t;

__global__ void absmax_both_kernel(const float* __restrict__ lhs,
                                   const float* __restrict__ rhs,
                                   unsigned* __restrict__ amax) {
    __shared__ float red[4];
    const int t = blockIdx.x & 1;
    const float4* x4 = (const float4*)(t ? rhs : lhs);
    const int bid = blockIdx.x >> 1;
    const int stride = (gridDim.x >> 1) * blockDim.x;  // 262144
    int i = bid * blockDim.x + threadIdx.x;
    float m0 = 0.0f, m1 = 0.0f, m2 = 0.0f, m3 = 0.0f;
    for (; i + 3 * stride < NELEM / 4; i += 4 * stride) {
        float4 a = x4[i];
        float4 b = x4[i + stride];
        float4 c = x4[i + 2 * stride];
        float4 d = x4[i + 3 * stride];
        m0 = fmaxf(m0, fmaxf(fmaxf(fabsf(a.x), fabsf(a.y)),
                             fmaxf(fabsf(a.z), fabsf(a.w))));
        m1 = fmaxf(m1, fmaxf(fmaxf(fabsf(b.x), fabsf(b.y)),
                             fmaxf(fabsf(b.z), fabsf(b.w))));
        m2 = fmaxf(m2, fmaxf(fmaxf(fabsf(c.x), fabsf(c.y)),
                             fmaxf(fabsf(c.z), fabsf(c.w))));
        m3 = fmaxf(m3, fmaxf(fmaxf(fabsf(d.x), fabsf(d.y)),
                             fmaxf(fabsf(d.z), fabsf(d.w))));
    }
    for (; i < NELEM / 4; i += stride) {
        float4 a = x4[i];
        m0 = fmaxf(m0, fmaxf(fmaxf(fabsf(a.x), fabsf(a.y)),
                             fmaxf(fabsf(a.z), fabsf(a.w))));
    }
    float m = fmaxf(fmaxf(m0, m1), fmaxf(m2, m3));
    for (int off = 32; off > 0; off >>= 1)
        m = fmaxf(m, __shfl_down(m, off, 64));
    const int lane = threadIdx.x & 63, wave = threadIdx.x >> 6;
    if (lane == 0) red[wave] = m;
    __syncthreads();
    if (threadIdx.x == 0) {
        float b = fmaxf(fmaxf(red[0], red[1]), fmaxf(red[2], red[3]));
        atomicMax(amax + t, __float_as_uint(b));  // |x|>=0: bits monotone as uint
    }
}

__device__ __forceinline__ int q8(float v, float s) {
    int r = __float2int_rn(v * s);  // RNE, matches jnp.round
    r = r < -127 ? -127 : r;
    r = r > 127 ? 127 : r;
    return r;
}

__device__ __forceinline__ int pack4(float a, float b, float c, float d,
                                     float s) {
    return (q8(a, s) & 0xff) | ((q8(b, s) & 0xff) << 8) |
           ((q8(c, s) & 0xff) << 16) | ((q8(d, s) & 0xff) << 24);
}

// Blocks [0,4096): A -> fragment layout (thread t = chunk c: contiguous 16B
// store to qA+c*16 from a 64B row-segment of lhs). Blocks [4096,8192): B ->
// verified LDS 64x64 transpose, frag-order output. (v10-v15 verified.)
__global__ void quant_kernel(const float* __restrict__ lhs,
                             const float* __restrict__ rhs,
                             int8_t* __restrict__ qA, int8_t* __restrict__ qT,
                             const unsigned* __restrict__ amax) {
    __shared__ int8_t sm[64][68];
    if (blockIdx.x < 4096) {
        const float s = 127.0f / fmaxf(__uint_as_float(amax[0]), 1e-12f);
        const int c = blockIdx.x * 256 + threadIdx.x;
        const int l = c & 63;
        const int ks_g = (c >> 6) & 127;
        const int mt_g = c >> 13;
        const int row = mt_g * 32 + (l & 31);
        const int kb = ks_g * 32 + (l >> 5) * 16;
        const float4* src = (const float4*)(lhs + (size_t)row * NROW + kb);
        float4 v0 = src[0], v1 = src[1], v2 = src[2], v3 = src[3];
        int4 w;
        w.x = pack4(v0.x, v0.y, v0.z, v0.w, s);
        w.y = pack4(v1.x, v1.y, v1.z, v1.w, s);
        w.z = pack4(v2.x, v2.y, v2.z, v2.w, s);
        w.w = pack4(v3.x, v3.y, v3.z, v3.w, s);
        *(int4*)(qA + (size_t)c * 16) = w;
    } else {
        const float s = 127.0f / fmaxf(__uint_as_float(amax[1]), 1e-12f);
        const int b = blockIdx.x - 4096;
        const int n0 = (b & 63) * 64, k0 = (b >> 6) * 64;
        const int rl = threadIdx.x >> 4;   // k row within 16-row slab
        const int nq = threadIdx.x & 15;   // float4 column
        for (int r = 0; r < 4; ++r) {
            const int kl = r * 16 + rl;
            float4 v = *(const float4*)(rhs + (size_t)(k0 + kl) * NROW + n0 + nq * 4);
            sm[nq * 4 + 0][kl] = (int8_t)q8(v.x, s);
            sm[nq * 4 + 1][kl] = (int8_t)q8(v.y, s);
            sm[nq * 4 + 2][kl] = (int8_t)q8(v.z, s);
            sm[nq * 4 + 3][kl] = (int8_t)q8(v.w, s);
        }
        __syncthreads();
        // Frag-order store: tile = 2 nt x 2 ks x 64 lanes = 256 chunks.
        const int nt_l = threadIdx.x >> 7;        // 0..1
        const int ks_l = (threadIdx.x >> 6) & 1;  // 0..1
        const int l = threadIdx.x & 63;
        const int n_loc = nt_l * 32 + (l & 31);
        const int k_loc = ks_l * 32 + (l >> 5) * 16;
        int4 w;  // 4x b32 reads, stride 17 words -> conflict-free
        w.x = *(const int*)&sm[n_loc][k_loc + 0];
        w.y = *(const int*)&sm[n_loc][k_loc + 4];
        w.z = *(const int*)&sm[n_loc][k_loc + 8];
        w.w = *(const int*)&sm[n_loc][k_loc + 12];
        const int nt_g = (b & 63) * 2 + nt_l;
        const int ks_g = (b >> 6) * 2 + ks_l;
        *(int4*)(qT + (((size_t)nt_g * 128 + ks_g) * 64 + l) * 16) = w;
    }
}

// 128x256 tile, 4 waves (1Mx4N of 128x64 = 4x2 of 32x32), BK=256 windows
// (2 K-tiles of 128 per barrier), 2 blocks/CU. A: double-buffered frag-
// ordered LDS (2 x 32 KiB), prefetch-1 window. B: global-direct register
// frags, 2-ks prefetch across 4 quarter-phases. Window w (tiles 2w, 2w+1):
// [stage A(w+1) both sub-tiles; {LOADB next; HALF} x4; vmcnt(4); s_barrier].
__global__ __launch_bounds__(256, 2) void gemm_i8_kernel(
    const int8_t* __restrict__ qA, const int8_t* __restrict__ qBT,
    float* __restrict__ out, const unsigned* __restrict__ amax) {
    __shared__ __align__(16) int8_t sA[2][32768];

    const int tid = threadIdx.x;
    const int lane = tid & 63;
    const int wn = tid >> 6;        // 0..3 : 64-col sub-tile

    // XCD-aware bijective swizzle (grid 512, 512%8==0): XCD k gets swz ids
    // [64k,64k+64) -> 4 contiguous 128-row M-panels (2 MB A) L2-resident.
    const int bid = blockIdx.y * 16 + blockIdx.x;
    const int swz = (bid & 7) * 64 + (bid >> 3);
    const int m0 = (swz >> 4) * 128, n0 = (swz & 15) * 256;

    const int rl = lane & 31;       // row within a 32-row MFMA tile
    const int hi = lane >> 5;       // k-half selector

    // A staging: per window, 2048 chunks x 16 B (2 sub-tiles x 4 mt x 4 ks x
    // 64 lanes), 8 per thread. Sub-tile h (K-tile 2w+h), j=0..3:
    // src = (m0/32 + j)*131072 + (2w+h)*4096 + tid*16;
    // dst = slot*32768 + h*16384 + j*4096 + tid*16.
    const gptr1_t pA0 = (gptr1_t)(qA + (size_t)(m0 / 32) * 131072 + tid * 16);
    int8_t* sAf = &sA[0][0];
    const int dst0 = tid * 16;

    auto stage = [&](int slot, int w1) {
#pragma unroll
        for (int h = 0; h < 2; ++h) {
            const int kb = (2 * w1 + h) * 4096;
#pragma unroll
            for (int j = 0; j < 4; ++j) {
                __builtin_amdgcn_global_load_lds(
                    pA0 + (size_t)j * 131072 + kb,
                    (lptr3_t)(sAf + slot * 32768 + h * 16384 + dst0 + j * 4096),
                    16, 0, 0);
            }
        }
    };

    // B global-direct: frag (n0/32 + wn*2 + nt, kt*4 + ks) at
    // pbW + nt*131072 + (kt*4+ks)*1024, per-lane +lane*16.
    const int8_t* pbW = qBT + (size_t)(n0 / 32 + wn * 2) * 131072 + lane * 16;

    int32x16 acc[4][2];
#pragma unroll
    for (int mt = 0; mt < 4; ++mt)
#pragma unroll
        for (int nt = 0; nt < 2; ++nt) acc[mt][nt] = (int32x16)(0);

    // ds_read base: A-frag (mt, ks) of sub-tile h at
    // h*16384 + (mt*4+ks)*1024 + lane*16.
    const int aBase = lane * 16;

    int32x4 B0[4], B1[4];  // [nt*2 + k] for a 2-ks quarter-phase

#define LOADB(B, KT, KS0)                                                     \
    {                                                                         \
        const int8_t* bp = pbW + (size_t)(KT)*4096 + (KS0)*1024;              \
        B[0] = *(const int32x4*)(bp);                                         \
        B[1] = *(const int32x4*)(bp + 1024);                                  \
        B[2] = *(const int32x4*)(bp + 131072);                                \
        B[3] = *(const int32x4*)(bp + 131072 + 1024);                         \
    }

#define HALF(APTR, B, KS0)                                                    \
    {                                                                         \
        _Pragma("unroll") for (int k = 0; k < 2; ++k) {                       \
            int32x4 af[4];                                                    \
            _Pragma("unroll") for (int mt = 0; mt < 4; ++mt) af[mt] =         \
                *(const int32x4*)((APTR) + aBase + mt * 4096 +                \
                                  ((KS0) + k) * 1024);                        \
            __builtin_amdgcn_s_setprio(1);                                    \
            _Pragma("unroll") for (int mt = 0; mt < 4; ++mt)                  \
                _Pragma("unroll") for (int nt = 0; nt < 2; ++nt)              \
                    acc[mt][nt] = __builtin_amdgcn_mfma_i32_32x32x32_i8(      \
                        af[mt], B[nt * 2 + k], acc[mt][nt], 0, 0, 0);         \
            __builtin_amdgcn_s_setprio(0);                                    \
        }                                                                     \
    }

    // Prologue: stage A window 0 (tiles 0,1); load B ks=0,1 of tile 0;
    // drain; barrier.
    stage(0, 0);
    __builtin_amdgcn_sched_barrier(0);
    LOADB(B0, 0, 0)
    asm volatile("s_waitcnt vmcnt(0)" ::: "memory");
    __builtin_amdgcn_sched_barrier(0);
    __builtin_amdgcn_s_barrier();
    __builtin_amdgcn_sched_barrier(0);

    // 16 windows of BK=256. Windows 0..14 stage the next window; 15 below.
#pragma unroll 1
    for (int w = 0; w < 15; ++w) {
        const int8_t* a0 = sAf + (w & 1) * 32768;
        const int8_t* a1 = a0 + 16384;
        stage((w + 1) & 1, w + 1);
        __builtin_amdgcn_sched_barrier(0);
        LOADB(B1, 2 * w, 2)           // tile 2w, ks 2,3
        HALF(a0, B0, 0)               // tile 2w, ks 0,1
        LOADB(B0, 2 * w + 1, 0)       // tile 2w+1, ks 0,1
        HALF(a0, B1, 2)               // tile 2w, ks 2,3
        LOADB(B1, 2 * w + 1, 2)       // tile 2w+1, ks 2,3
        HALF(a1, B0, 0)               // tile 2w+1, ks 0,1
        LOADB(B0, 2 * w + 2, 0)       // next window, tile 2w+2, ks 0,1
        HALF(a1, B1, 2)               // tile 2w+1, ks 2,3 (wait drains stage)
        asm volatile("s_waitcnt vmcnt(4)" ::: "memory");  // keep only B0(next)
        __builtin_amdgcn_sched_barrier(0);
        __builtin_amdgcn_s_barrier();
        __builtin_amdgcn_sched_barrier(0);
    }
    // Window 15 (slot 1, tiles 30,31): no staging, no next-window B.
    {
        const int8_t* a0 = sAf + 32768;
        const int8_t* a1 = a0 + 16384;
        LOADB(B1, 30, 2)
        HALF(a0, B0, 0)
        LOADB(B0, 31, 0)
        HALF(a0, B1, 2)
        LOADB(B1, 31, 2)
        HALF(a1, B0, 0)
        HALF(a1, B1, 2)
    }

    // Epilogue: dequant + store. 32x32 C/D layout: col = lane&31,
    // row = (reg&3) + 8*(reg>>2) + 4*(lane>>5). (v8/v12-v15-verified.)
    const float ls = 127.0f / fmaxf(__uint_as_float(amax[0]), 1e-12f);
    const float rs = 127.0f / fmaxf(__uint_as_float(amax[1]), 1e-12f);
    const float inv = 1.0f / (ls * rs);
#pragma unroll
    for (int mt = 0; mt < 4; ++mt)
#pragma unroll
        for (int nt = 0; nt < 2; ++nt)
#pragma unroll
            for (int reg = 0; reg < 16; ++reg) {
                const int row = m0 + mt * 32 + (reg & 3) + 8 * (reg >> 2) +
                                4 * hi;
                const int col = n0 + wn * 64 + nt * 32 + rl;
                out[(size_t)row * NROW + col] = (float)acc[mt][nt][reg] * inv;
            }
#undef LOADB
#undef HALF
}

extern "C" void kernel_launch(void* const* d_in, const int* in_sizes, int n_in,
                              void* d_out, int out_size, void* d_ws,
                              size_t ws_size, hipStream_t stream) {
    const float* lhs = (const float*)d_in[0];
    const float* rhs = (const float*)d_in[1];
    float* out = (float*)d_out;

    int8_t* qA = (int8_t*)d_ws;
    int8_t* qBT = qA + (size_t)16 * 1024 * 1024;
    unsigned* amax = (unsigned*)(qBT + (size_t)16 * 1024 * 1024);

    hipMemsetAsync(amax, 0, 8, stream);
    absmax_both_kernel<<<2048, 256, 0, stream>>>(lhs, rhs, amax);
    quant_kernel<<<4096 + 4096, 256, 0, stream>>>(lhs, rhs, qA, qBT, amax);
    gemm_i8_kernel<<<dim3(16, 32), 256, 0, stream>>>(qA, qBT, out, amax);
}